// Round 4
// baseline (1072.453 us; speedup 1.0000x reference)
//
#include <hip/hip_runtime.h>
#include <hip/hip_fp16.h>

// GatedAxialAttentionWidthMultiHead — MI355X fused implementation (round 4)
// Fix vs r3: Gv2 gate applied on rv AXIS 0 (= c/head_dim per right-aligned
// broadcasting of (16,1,1,1) against 4-dim rv), not axis 1. All other gates
// (Gq, Gk, Gv1) multiply 5-dim tensors and correctly land on h.
//
// Pipeline:
//  1. cvt_rqrk : rq*Gq[h] -> fp16,  rk*(Gk[h]/16) -> fp16          (gates folded)
//  2. cvt_rv_t : rv*Gv2[c] -> fp16, transposed to [h][c][w][j]     (coalesced PV loads)
//  3. qkv_gemm : q/k/v = W @ x   (fp32 compute, fp16 out)
//  4. attn     : per block (h,i, all 4 n): S=(qk + q*rq' + k*rk')/16 (1/16 in q),
//                softmax over j (per-w independent), out = P@(Gv1 v) + P*rv'
//  5. wo_gemm  : out = wo @ att  (fp16 in, fp32 compute/out)
//
// ws layout (halves): q16 k16 v16(=att16) [16777216 each] + rq16 rk16 rv16 [4194304 each]
// total = 125,829,120 bytes = 120 MB

#define NB   4
#define CH   256
#define HH   128
#define WW   128
#define PIX  16384      // HH*WW
#define CHW  4194304    // CH*PIX
#define RSZ  4194304    // 16*16*128*128

struct __align__(8)  h4_t { __half2 a, b; };
struct __align__(16) h8_t { __half2 a, b, c, d; };

__device__ __forceinline__ __half2 mkh2(float x, float y) {
  __half2 r; r.x = __float2half_rn(x); r.y = __float2half_rn(y); return r;
}

// ---------------------------------------------------------------- conversions
__global__ __launch_bounds__(256) void cvt_rqrk(
    const float* __restrict__ rq, const float* __restrict__ rk,
    const float* __restrict__ Gq, const float* __restrict__ Gk,
    __half* __restrict__ oq, __half* __restrict__ ok) {
  const int e = (blockIdx.x * 256 + threadIdx.x) * 4;   // layout ((c*16+h)*128+j)*128+w
  const int h = (e >> 14) & 15;                          // axis1 = num_heads (5-dim bcast)
  if (blockIdx.y == 0) {
    const float g = Gq[h];
    const float4 xv = *(const float4*)&rq[e];
    h4_t o; o.a = mkh2(xv.x * g, xv.y * g); o.b = mkh2(xv.z * g, xv.w * g);
    *(h4_t*)&oq[e] = o;
  } else {
    const float g = Gk[h] * 0.0625f;                     // Gk/D folded
    const float4 xv = *(const float4*)&rk[e];
    h4_t o; o.a = mkh2(xv.x * g, xv.y * g); o.b = mkh2(xv.z * g, xv.w * g);
    *(h4_t*)&ok[e] = o;
  }
}

// rv[c][h][j][w] * Gv2[c]  ->  rv16[h][c][w][j]   (32x32 LDS tile transpose)
// NOTE: Gv2 (16,1,1,1) right-aligned against 4-dim rv -> gate indexes AXIS 0 (c).
__global__ __launch_bounds__(256) void cvt_rv_t(
    const float* __restrict__ rv, const float* __restrict__ Gv2,
    __half* __restrict__ o) {
  __shared__ float t[32][33];
  const int b = blockIdx.x;                 // 16h*16c*4jt*4wt = 4096
  const int wt = b & 3, jt = (b >> 2) & 3, c = (b >> 4) & 15, h = b >> 8;
  const int tx = threadIdx.x & 31, r0 = threadIdx.x >> 5;
  const float g = Gv2[c];                   // axis-0 gate (the r3 bug was Gv2[h])
  #pragma unroll
  for (int rr = 0; rr < 4; ++rr) {
    const int j = jt * 32 + r0 + rr * 8;
    t[r0 + rr * 8][tx] = rv[((c * 16 + h) * HH + j) * WW + wt * 32 + tx] * g;
  }
  __syncthreads();
  #pragma unroll
  for (int rr = 0; rr < 4; ++rr) {
    const int w = wt * 32 + r0 + rr * 8;
    o[((h * 16 + c) * WW + w) * WW + jt * 32 + tx] = __float2half_rn(t[tx][r0 + rr * 8]);
  }
}

// ---------------------------------------------------------------- GEMM (256 x 16384, K=256)
template<typename TB, typename TO>
__device__ __forceinline__ void gemm_body(const TB* __restrict__ X,
                                          const float* __restrict__ Wm,
                                          TO* __restrict__ Y) {
  __shared__ float As[16][136];   // A transposed [k][m], pad 8
  __shared__ float Bs[16][132];   // [k][n], pad 4
  const int tid = threadIdx.x;
  const int p0 = blockIdx.x * 128;
  const int bm = blockIdx.y * 128;
  const int tn = tid & 15, tm = tid >> 4;
  float acc[8][8] = {};
  for (int kt = 0; kt < 16; ++kt) {
    #pragma unroll
    for (int u = 0; u < 2; ++u) {          // stage A: 128 rows x 16 k (transposed store)
      const int fid = tid + 256 * u;
      const int row = fid >> 2, c4 = (fid & 3) * 4;
      const float4 a = *(const float4*)&Wm[(bm + row) * CH + kt * 16 + c4];
      As[c4 + 0][row] = a.x; As[c4 + 1][row] = a.y;
      As[c4 + 2][row] = a.z; As[c4 + 3][row] = a.w;
    }
    {                                       // stage B: 16 k x 128 pixels
      const int kr = tid >> 4, pc = (tid & 15) * 8;
      if constexpr (sizeof(TB) == 2) {
        const h8_t hv = *(const h8_t*)&X[(kt * 16 + kr) * PIX + p0 + pc];
        const float2 f0 = __half22float2(hv.a), f1 = __half22float2(hv.b);
        const float2 f2 = __half22float2(hv.c), f3 = __half22float2(hv.d);
        const float4 b0 = {f0.x, f0.y, f1.x, f1.y};
        const float4 b1 = {f2.x, f2.y, f3.x, f3.y};
        *(float4*)&Bs[kr][pc]     = b0;
        *(float4*)&Bs[kr][pc + 4] = b1;
      } else {
        const TB* xp = &X[(kt * 16 + kr) * PIX + p0 + pc];
        *(float4*)&Bs[kr][pc]     = *(const float4*)&xp[0];
        *(float4*)&Bs[kr][pc + 4] = *(const float4*)&xp[4];
      }
    }
    __syncthreads();
    #pragma unroll
    for (int kk = 0; kk < 16; ++kk) {
      float a[8], b[8];
      *(float4*)&a[0] = *(const float4*)&As[kk][tm * 8];
      *(float4*)&a[4] = *(const float4*)&As[kk][tm * 8 + 4];
      *(float4*)&b[0] = *(const float4*)&Bs[kk][tn * 8];
      *(float4*)&b[4] = *(const float4*)&Bs[kk][tn * 8 + 4];
      #pragma unroll
      for (int r = 0; r < 8; ++r)
        #pragma unroll
        for (int cc = 0; cc < 8; ++cc)
          acc[r][cc] += a[r] * b[cc];
    }
    __syncthreads();
  }
  #pragma unroll
  for (int r = 0; r < 8; ++r) {
    TO* yp = &Y[(bm + tm * 8 + r) * PIX + p0 + tn * 8];
    if constexpr (sizeof(TO) == 2) {
      h4_t o0, o1;
      o0.a = mkh2(acc[r][0], acc[r][1]); o0.b = mkh2(acc[r][2], acc[r][3]);
      o1.a = mkh2(acc[r][4], acc[r][5]); o1.b = mkh2(acc[r][6], acc[r][7]);
      *(h4_t*)&yp[0] = o0;
      *(h4_t*)&yp[4] = o1;
    } else {
      const float4 s0 = {acc[r][0], acc[r][1], acc[r][2], acc[r][3]};
      const float4 s1 = {acc[r][4], acc[r][5], acc[r][6], acc[r][7]};
      *(float4*)&yp[0] = s0;
      *(float4*)&yp[4] = s1;
    }
  }
}

__global__ __launch_bounds__(256) void qkv_gemm(
    const float* __restrict__ x,
    const float* __restrict__ wq, const float* __restrict__ wk, const float* __restrict__ wv,
    __half* __restrict__ q, __half* __restrict__ k, __half* __restrict__ v) {
  const int z = blockIdx.z, n = z / 3, pr = z - n * 3;
  const float* W = (pr == 0) ? wq : (pr == 1 ? wk : wv);
  __half* Y = (pr == 0) ? q : (pr == 1 ? k : v);
  gemm_body<float, __half>(x + (size_t)n * CHW, W, Y + (size_t)n * CHW);
}

__global__ __launch_bounds__(256) void wo_gemm(
    const __half* __restrict__ att, const float* __restrict__ wo, float* __restrict__ out) {
  const int n = blockIdx.z;
  gemm_body<__half, float>(att + (size_t)n * CHW, wo, out + (size_t)n * CHW);
}

// ---------------------------------------------------------------- fused attention
// block = (h, i), all 4 batches; w tiled by 32; softmax over j per w-column.
__global__ __launch_bounds__(512) void attn_fused(
    const __half* __restrict__ Q, const __half* __restrict__ Kv, const __half* __restrict__ V,
    const __half* __restrict__ RQ, const __half* __restrict__ RK, const __half* __restrict__ RVT,
    const float* __restrict__ Gv1, __half* __restrict__ ATT) {
  __shared__ float q_s[4][16][128];   // q / 16
  __shared__ float k_s[4][16][128];   // k (serves both j and w roles)
  __shared__ float v_s[4][16][36];    // Gv1 * v, current w-tile slice
  __shared__ float S_s[4][32][130];   // S / P transposed: [p][w_local][j]

  const int tid = threadIdx.x;
  const int id = blockIdx.x;
  const int sid = (id & 7) * 256 + (id >> 3);    // XCD-contiguous heads
  const int h = sid >> 7, ii = sid & 127;

  for (int idx = tid; idx < 2048; idx += 512) {  // stage q,k full rows (fp16 -> fp32)
    const int p = idx >> 9, c = (idx >> 5) & 15, j4 = (idx & 31) * 4;
    const int g = ((p * CH + h * 16 + c) * HH + ii) * WW + j4;
    const h4_t qh = *(const h4_t*)&Q[g];
    const h4_t kh = *(const h4_t*)&Kv[g];
    const float2 q01 = __half22float2(qh.a), q23 = __half22float2(qh.b);
    const float2 k01 = __half22float2(kh.a), k23 = __half22float2(kh.b);
    const float4 qv = {q01.x * 0.0625f, q01.y * 0.0625f, q23.x * 0.0625f, q23.y * 0.0625f};
    const float4 kv = {k01.x, k01.y, k23.x, k23.y};
    *(float4*)&q_s[p][c][j4] = qv;
    *(float4*)&k_s[p][c][j4] = kv;
  }

  float o1[4][2][2] = {};
  float o2[4][2][2] = {};
  const float gv1 = Gv1[h];

  const int jb = tid >> 3, wb = tid & 7;     // S-phase decode
  const int j0 = jb * 2, wl = wb * 4;
  const int oc = tid >> 5, jg = tid & 31;    // out-phase decode

  __syncthreads();

  for (int wt = 0; wt < 4; ++wt) {
    const int w0 = wt * 32;
    {                                         // stage v slice (x Gv1)
      const int p = tid >> 7, c = (tid >> 3) & 15, w4 = (tid & 7) * 4;
      const int g = ((p * CH + h * 16 + c) * HH + ii) * WW + w0 + w4;
      const h4_t vh = *(const h4_t*)&V[g];
      const float2 v01 = __half22float2(vh.a), v23 = __half22float2(vh.b);
      const float4 vv = {v01.x * gv1, v01.y * gv1, v23.x * gv1, v23.y * gv1};
      *(float4*)&v_s[p][c][w4] = vv;
    }
    // ---- S = q^T k /D + q.rq' + k.rk'   (thread: 2 j x 4 w, x4 batches)
    float sacc[4][2][4] = {};
    #pragma unroll 2
    for (int c = 0; c < 16; ++c) {
      const int rb = (c * 16 + h) * PIX + w0 + wl;
      const h4_t hq0 = *(const h4_t*)&RQ[rb + (j0    ) * WW];
      const h4_t hq1 = *(const h4_t*)&RQ[rb + (j0 + 1) * WW];
      const h4_t hk0 = *(const h4_t*)&RK[rb + (j0    ) * WW];
      const h4_t hk1 = *(const h4_t*)&RK[rb + (j0 + 1) * WW];
      const float2 a0 = __half22float2(hq0.a), b0 = __half22float2(hq0.b);
      const float2 a1 = __half22float2(hq1.a), b1 = __half22float2(hq1.b);
      const float2 c0 = __half22float2(hk0.a), d0 = __half22float2(hk0.b);
      const float2 c1 = __half22float2(hk1.a), d1 = __half22float2(hk1.b);
      const float rq0[4] = {a0.x, a0.y, b0.x, b0.y};
      const float rq1[4] = {a1.x, a1.y, b1.x, b1.y};
      const float rk0[4] = {c0.x, c0.y, d0.x, d0.y};
      const float rk1[4] = {c1.x, c1.y, d1.x, d1.y};
      #pragma unroll
      for (int p = 0; p < 4; ++p) {
        const float2 qj = *(const float2*)&q_s[p][c][j0];
        const float2 kj = *(const float2*)&k_s[p][c][j0];
        const float4 kwv = *(const float4*)&k_s[p][c][w0 + wl];
        const float kw[4] = {kwv.x, kwv.y, kwv.z, kwv.w};
        #pragma unroll
        for (int wi = 0; wi < 4; ++wi) {
          sacc[p][0][wi] += qj.x * kw[wi] + qj.x * rq0[wi] + kj.x * rk0[wi];
          sacc[p][1][wi] += qj.y * kw[wi] + qj.y * rq1[wi] + kj.y * rk1[wi];
        }
      }
    }
    #pragma unroll
    for (int p = 0; p < 4; ++p)
      #pragma unroll
      for (int wi = 0; wi < 4; ++wi) {
        const float2 s2 = {sacc[p][0][wi], sacc[p][1][wi]};
        *(float2*)&S_s[p][wl + wi][j0] = s2;
      }
    __syncthreads();
    // ---- softmax over j per (p,w) row; 4 lanes per row
    {
      const int row = tid >> 2, sub = tid & 3;
      float* Sr = &S_s[row >> 5][row & 31][0];
      const int jbase = sub * 32;
      float m = -1e30f;
      #pragma unroll
      for (int s = 0; s < 16; ++s) {
        const float2 xv = *(const float2*)&Sr[jbase + s * 2];
        m = fmaxf(m, fmaxf(xv.x, xv.y));
      }
      m = fmaxf(m, __shfl_xor(m, 1));
      m = fmaxf(m, __shfl_xor(m, 2));
      float Z = 0.f;
      #pragma unroll
      for (int s = 0; s < 16; ++s) {
        float2 xv = *(const float2*)&Sr[jbase + s * 2];
        xv.x = __expf(xv.x - m); xv.y = __expf(xv.y - m);
        Z += xv.x + xv.y;
        *(float2*)&Sr[jbase + s * 2] = xv;
      }
      Z += __shfl_xor(Z, 1);
      Z += __shfl_xor(Z, 2);
      const float rz = 1.f / Z;
      #pragma unroll
      for (int s = 0; s < 16; ++s) {
        float2 xv = *(const float2*)&Sr[jbase + s * 2];
        xv.x *= rz; xv.y *= rz;
        *(float2*)&Sr[jbase + s * 2] = xv;
      }
    }
    __syncthreads();
    // ---- out1 += P @ v',  out2 += P * rv'   (thread: c, 2 j-halves x 2 j)
    {
      const int rvb = ((h * 16 + oc) * WW + w0) * WW + jg * 2;
      #pragma unroll 4
      for (int w2 = 0; w2 < 32; ++w2) {
        float vv[4];
        #pragma unroll
        for (int p = 0; p < 4; ++p) vv[p] = v_s[p][oc][w2];
        #pragma unroll
        for (int jh = 0; jh < 2; ++jh) {
          const float2 rvf = __half22float2(*(const __half2*)&RVT[rvb + w2 * WW + jh * 64]);
          #pragma unroll
          for (int p = 0; p < 4; ++p) {
            const float2 P2 = *(const float2*)&S_s[p][w2][jh * 64 + jg * 2];
            o1[p][jh][0] += P2.x * vv[p];
            o1[p][jh][1] += P2.y * vv[p];
            o2[p][jh][0] += P2.x * rvf.x;
            o2[p][jh][1] += P2.y * rvf.y;
          }
        }
      }
    }
    __syncthreads();
  }
  #pragma unroll
  for (int p = 0; p < 4; ++p)
    #pragma unroll
    for (int jh = 0; jh < 2; ++jh) {
      const float ox = o1[p][jh][0] + o2[p][jh][0];
      const float oy = o1[p][jh][1] + o2[p][jh][1];
      *(__half2*)&ATT[((p * CH + h * 16 + oc) * HH + ii) * WW + jh * 64 + jg * 2] = mkh2(ox, oy);
    }
}

// ---------------------------------------------------------------- launch
extern "C" void kernel_launch(void* const* d_in, const int* in_sizes, int n_in,
                              void* d_out, int out_size, void* d_ws, size_t ws_size,
                              hipStream_t stream) {
  (void)in_sizes; (void)n_in; (void)out_size; (void)ws_size;
  const float* x   = (const float*)d_in[0];
  const float* wq  = (const float*)d_in[1];
  const float* wk  = (const float*)d_in[2];
  const float* wv  = (const float*)d_in[3];
  const float* wo  = (const float*)d_in[4];
  const float* rq  = (const float*)d_in[5];
  const float* rk  = (const float*)d_in[6];
  const float* rv  = (const float*)d_in[7];
  const float* Gq  = (const float*)d_in[8];
  const float* Gk  = (const float*)d_in[9];
  const float* Gv1 = (const float*)d_in[10];
  const float* Gv2 = (const float*)d_in[11];
  float* out = (float*)d_out;

  __half* q16  = (__half*)d_ws;                       // 120 MB total
  __half* k16  = q16 + (size_t)NB * CHW;
  __half* v16  = k16 + (size_t)NB * CHW;              // att aliases v16 (safe: see analysis)
  __half* rq16 = v16 + (size_t)NB * CHW;
  __half* rk16 = rq16 + (size_t)RSZ;
  __half* rv16 = rk16 + (size_t)RSZ;

  cvt_rqrk<<<dim3(RSZ / 1024, 2), dim3(256), 0, stream>>>(rq, rk, Gq, Gk, rq16, rk16);
  cvt_rv_t<<<dim3(4096), dim3(256), 0, stream>>>(rv, Gv2, rv16);
  qkv_gemm<<<dim3(128, 2, 12), dim3(256), 0, stream>>>(x, wq, wk, wv, q16, k16, v16);
  attn_fused<<<dim3(2048), dim3(512), 0, stream>>>(q16, k16, v16, rq16, rk16, rv16, Gv1, v16);
  wo_gemm<<<dim3(128, 2, 4), dim3(256), 0, stream>>>(v16, wo, out);
}

// Round 8
// 747.865 us; speedup vs baseline: 1.4340x; 1.4340x over previous
//
#include <hip/hip_runtime.h>
#include <hip/hip_fp16.h>

// GatedAxialAttentionWidthMultiHead — MI355X (round 8 = round 5 resubmit; r5/r6/r7 never
// ran: broker timeouts / container failure — kernel has never executed)
// vs r4: (1) attn p-split: block=(h,i,2 batches), LDS 138->69 KB => 2 blocks/CU
//        (2) qkv/wo projections moved to fp16 MFMA (v_mfma_f32_16x16x32_f16)
//        (3) merged PV accumulators; XCD-swizzled GEMM grid
// ws: q16 k16 v16(att) [16,777,216 h each] + rq16 rk16 rv16 [4,194,304 h] + W16 [262,144 h]
//   = 126,353,408 B

#define NB   4
#define CH   256
#define HH   128
#define WW   128
#define PIX  16384
#define CHW  4194304
#define RSZ  4194304

typedef _Float16 half8_t __attribute__((ext_vector_type(8)));
typedef float    f32x4_t __attribute__((ext_vector_type(4)));

struct __align__(8) h4_t { __half2 a, b; };

__device__ __forceinline__ __half2 mkh2(float x, float y) {
  __half2 r; r.x = __float2half_rn(x); r.y = __float2half_rn(y); return r;
}

// ---------------------------------------------------------------- conversions
__global__ __launch_bounds__(256) void cvt_w(
    const float* __restrict__ wq, const float* __restrict__ wk,
    const float* __restrict__ wv, const float* __restrict__ wo,
    __half* __restrict__ W16) {
  const int e = (blockIdx.x * 256 + threadIdx.x) * 4;   // 262144 total
  const int row = e >> 8;
  const float* src = row < 256 ? wq : row < 512 ? wk : row < 768 ? wv : wo;
  const float4 xv = *(const float4*)&src[e & 65535];
  h4_t o; o.a = mkh2(xv.x, xv.y); o.b = mkh2(xv.z, xv.w);
  *(h4_t*)&W16[e] = o;
}

__global__ __launch_bounds__(256) void cvt_rqrk(
    const float* __restrict__ rq, const float* __restrict__ rk,
    const float* __restrict__ Gq, const float* __restrict__ Gk,
    __half* __restrict__ oq, __half* __restrict__ ok) {
  const int e = (blockIdx.x * 256 + threadIdx.x) * 4;   // ((c*16+h)*128+j)*128+w
  const int h = (e >> 14) & 15;
  if (blockIdx.y == 0) {
    const float g = Gq[h];
    const float4 xv = *(const float4*)&rq[e];
    h4_t o; o.a = mkh2(xv.x * g, xv.y * g); o.b = mkh2(xv.z * g, xv.w * g);
    *(h4_t*)&oq[e] = o;
  } else {
    const float g = Gk[h] * 0.0625f;                    // Gk/D folded
    const float4 xv = *(const float4*)&rk[e];
    h4_t o; o.a = mkh2(xv.x * g, xv.y * g); o.b = mkh2(xv.z * g, xv.w * g);
    *(h4_t*)&ok[e] = o;
  }
}

// rv[c][h][j][w] * Gv2[c]  ->  rv16[h][c][w][j]  (Gv2 right-aligned => axis 0 = c)
__global__ __launch_bounds__(256) void cvt_rv_t(
    const float* __restrict__ rv, const float* __restrict__ Gv2,
    __half* __restrict__ o) {
  __shared__ float t[32][33];
  const int b = blockIdx.x;
  const int wt = b & 3, jt = (b >> 2) & 3, c = (b >> 4) & 15, h = b >> 8;
  const int tx = threadIdx.x & 31, r0 = threadIdx.x >> 5;
  const float g = Gv2[c];
  #pragma unroll
  for (int rr = 0; rr < 4; ++rr) {
    const int j = jt * 32 + r0 + rr * 8;
    t[r0 + rr * 8][tx] = rv[((c * 16 + h) * HH + j) * WW + wt * 32 + tx] * g;
  }
  __syncthreads();
  #pragma unroll
  for (int rr = 0; rr < 4; ++rr) {
    const int w = wt * 32 + r0 + rr * 8;
    o[((h * 16 + c) * WW + w) * WW + jt * 32 + tx] = __float2half_rn(t[tx][r0 + rr * 8]);
  }
}

// ---------------------------------------------------------------- fp16 MFMA GEMM
// C[m 128][n 128] tile, BK=32, 4 waves (2x2), per-wave 64x64 = 4x4 frags of 16x16x32.
// A = W16 [rows][256] fp16 row-major; B = x (f32) or att (fp16), layout [k][pix].
// Bs transposed at staging ([n][k], row stride 36h: scalar writes 2-way, b64 frag reads
// bank-starts n*18%32 = 16-distinct => conflict-free).
template<int BF32, int OUTF>
__global__ __launch_bounds__(256, 3) void gemm16(
    const __half* __restrict__ A16, const float* __restrict__ Bf,
    const __half* __restrict__ Bh, __half* __restrict__ Oq,
    __half* __restrict__ Ok, __half* __restrict__ Ov,
    float* __restrict__ Of, int bmBase, int ny) {
  __shared__ __half As[128][40];
  __shared__ __half Bs[128][36];
  const int tid = threadIdx.x;
  const int nwg = 128 * ny * NB;
  const int id = blockIdx.x;
  const int sid = (id & 7) * (nwg >> 3) + (id >> 3);   // XCD-contiguous chunks
  const int nb = sid / (128 * ny);
  const int rest = sid - nb * 128 * ny;
  const int bx = rest / ny, my = rest - bx * ny;       // y-siblings adjacent (B-panel reuse)
  const int p0 = bx * 128;
  const int bm = bmBase + my * 128;

  const int wave = tid >> 6, lane = tid & 63;
  const int wm = wave >> 1, wn = wave & 1;
  const int l15 = lane & 15, l4 = lane >> 4;

  const float*  Bfp = BF32 ? Bf + (size_t)nb * CHW : nullptr;
  const __half* Bhp = BF32 ? nullptr : Bh + (size_t)nb * CHW;
  const int nB = tid & 31, kg = (tid >> 5) * 4;
  const int mA = tid >> 1, khA = tid & 1;

  f32x4_t acc[4][4];
  #pragma unroll
  for (int mf = 0; mf < 4; ++mf)
    #pragma unroll
    for (int nf = 0; nf < 4; ++nf)
      acc[mf][nf] = (f32x4_t){0.f, 0.f, 0.f, 0.f};

  for (int kt = 0; kt < 8; ++kt) {
    const int k0 = kt * 32;
    {  // A stage: 32B per thread
      const float4* src = (const float4*)&A16[(size_t)(bm + mA) * 256 + k0 + khA * 16];
      *(float4*)&As[mA][khA * 16]     = src[0];
      *(float4*)&As[mA][khA * 16 + 8] = src[1];
    }
    // B stage (transposed): 16 scalar loads + 16 b16 writes per thread
    #pragma unroll
    for (int ni = 0; ni < 4; ++ni)
      #pragma unroll
      for (int ki = 0; ki < 4; ++ki) {
        const int n = nB + ni * 32, k = kg + ki;
        if (BF32)
          Bs[n][k] = __float2half_rn(Bfp[(size_t)(k0 + k) * PIX + p0 + n]);
        else
          Bs[n][k] = Bhp[(size_t)(k0 + k) * PIX + p0 + n];
      }
    __syncthreads();
    half8_t af[4], bfr[4];
    #pragma unroll
    for (int mf = 0; mf < 4; ++mf)
      af[mf] = *(const half8_t*)&As[wm * 64 + mf * 16 + l15][l4 * 8];
    #pragma unroll
    for (int nf = 0; nf < 4; ++nf) {
      union { float2 f2[2]; half8_t h; } u;
      const __half* bp = &Bs[wn * 64 + nf * 16 + l15][l4 * 8];
      u.f2[0] = *(const float2*)bp;
      u.f2[1] = *(const float2*)(bp + 4);
      bfr[nf] = u.h;
    }
    #pragma unroll
    for (int mf = 0; mf < 4; ++mf)
      #pragma unroll
      for (int nf = 0; nf < 4; ++nf)
        acc[mf][nf] = __builtin_amdgcn_mfma_f32_16x16x32_f16(af[mf], bfr[nf], acc[mf][nf], 0, 0, 0);
    __syncthreads();
  }

  const int pxW = p0 + wn * 64;
  if (OUTF) {                      // f32 out (wo)
    float* Yp = Of + (size_t)nb * CHW;
    const int chB = my * 128 + wm * 64;
    #pragma unroll
    for (int mf = 0; mf < 4; ++mf)
      #pragma unroll
      for (int nf = 0; nf < 4; ++nf)
        #pragma unroll
        for (int r = 0; r < 4; ++r)
          Yp[(size_t)(chB + mf * 16 + l4 * 4 + r) * PIX + pxW + nf * 16 + l15] = acc[mf][nf][r];
  } else {                         // fp16 out (q/k/v select by m-tile)
    __half* Y = (my < 2) ? Oq : (my < 4) ? Ok : Ov;
    __half* Yp = Y + (size_t)nb * CHW;
    const int chB = (my & 1) * 128 + wm * 64;
    #pragma unroll
    for (int mf = 0; mf < 4; ++mf)
      #pragma unroll
      for (int nf = 0; nf < 4; ++nf)
        #pragma unroll
        for (int r = 0; r < 4; ++r)
          Yp[(size_t)(chB + mf * 16 + l4 * 4 + r) * PIX + pxW + nf * 16 + l15] =
              __float2half_rn(acc[mf][nf][r]);
  }
}

// ---------------------------------------------------------------- fused attention
// block = (h, i, 2 batches); w tiled by 32; softmax over j per w-column.
// LDS 70,656 B -> 2 blocks/CU (16 waves).
__global__ __launch_bounds__(512, 4) void attn_fused(
    const __half* __restrict__ Q, const __half* __restrict__ Kv, const __half* __restrict__ V,
    const __half* __restrict__ RQ, const __half* __restrict__ RK, const __half* __restrict__ RVT,
    const float* __restrict__ Gv1, __half* __restrict__ ATT) {
  __shared__ float q_s[2][16][128];   // q/16
  __shared__ float k_s[2][16][128];
  __shared__ float v_s[2][16][36];    // Gv1*v, current w-tile
  __shared__ float S_s[2][32][130];   // S/P: [p][w_local][j]

  const int tid = threadIdx.x;
  const int id = blockIdx.x;
  const int sid = (id & 7) * 512 + (id >> 3);   // 4096 % 8 == 0, bijective
  const int h = sid >> 8;
  const int rest = sid & 255;
  const int ii = rest >> 1;
  const int pb = (rest & 1) * 2;                // batch pair base

  for (int idx = tid; idx < 1024; idx += 512) { // stage q,k (2 batches)
    const int p = idx >> 9, c = (idx >> 5) & 15, j4 = (idx & 31) * 4;
    const size_t g = ((size_t)((pb + p) * CH + h * 16 + c) * HH + ii) * WW + j4;
    const h4_t qh = *(const h4_t*)&Q[g];
    const h4_t kh = *(const h4_t*)&Kv[g];
    const float2 q01 = __half22float2(qh.a), q23 = __half22float2(qh.b);
    const float2 k01 = __half22float2(kh.a), k23 = __half22float2(kh.b);
    const float4 qv = {q01.x * 0.0625f, q01.y * 0.0625f, q23.x * 0.0625f, q23.y * 0.0625f};
    const float4 kv = {k01.x, k01.y, k23.x, k23.y};
    *(float4*)&q_s[p][c][j4] = qv;
    *(float4*)&k_s[p][c][j4] = kv;
  }

  float o[2][2][2] = {};                        // merged: out = sum_w P*(v'+rv')
  const float gv1 = Gv1[h];

  const int jb = tid >> 3, wb = tid & 7;
  const int j0 = jb * 2, wl = wb * 4;
  const int oc = tid >> 5, jg = tid & 31;

  __syncthreads();

  for (int wt = 0; wt < 4; ++wt) {
    const int w0 = wt * 32;
    {                                           // stage v slice (x Gv1): 1024 h2-elems
      const int p = tid >> 8, c = (tid >> 4) & 15, w2 = (tid & 15) * 2;
      const size_t g = ((size_t)((pb + p) * CH + h * 16 + c) * HH + ii) * WW + w0 + w2;
      const float2 vf = __half22float2(*(const __half2*)&V[g]);
      const float2 vv = {vf.x * gv1, vf.y * gv1};
      *(float2*)&v_s[p][c][w2] = vv;
    }
    // ---- S = qk/16 + q.rq' + k.rk'  (thread: 2j x 4w x 2p)
    float sacc[2][2][4] = {};
    #pragma unroll 2
    for (int c = 0; c < 16; ++c) {
      const int rb = (c * 16 + h) * PIX + w0 + wl;
      const h4_t hq0 = *(const h4_t*)&RQ[rb + j0 * WW];
      const h4_t hq1 = *(const h4_t*)&RQ[rb + (j0 + 1) * WW];
      const h4_t hk0 = *(const h4_t*)&RK[rb + j0 * WW];
      const h4_t hk1 = *(const h4_t*)&RK[rb + (j0 + 1) * WW];
      const float2 a0 = __half22float2(hq0.a), b0 = __half22float2(hq0.b);
      const float2 a1 = __half22float2(hq1.a), b1 = __half22float2(hq1.b);
      const float2 c0 = __half22float2(hk0.a), d0 = __half22float2(hk0.b);
      const float2 c1 = __half22float2(hk1.a), d1 = __half22float2(hk1.b);
      const float rq0[4] = {a0.x, a0.y, b0.x, b0.y};
      const float rq1[4] = {a1.x, a1.y, b1.x, b1.y};
      const float rk0[4] = {c0.x, c0.y, d0.x, d0.y};
      const float rk1[4] = {c1.x, c1.y, d1.x, d1.y};
      #pragma unroll
      for (int p = 0; p < 2; ++p) {
        const float2 qj = *(const float2*)&q_s[p][c][j0];
        const float2 kj = *(const float2*)&k_s[p][c][j0];
        const float4 kwv = *(const float4*)&k_s[p][c][w0 + wl];
        const float kw[4] = {kwv.x, kwv.y, kwv.z, kwv.w};
        #pragma unroll
        for (int wi = 0; wi < 4; ++wi) {
          sacc[p][0][wi] += qj.x * kw[wi] + qj.x * rq0[wi] + kj.x * rk0[wi];
          sacc[p][1][wi] += qj.y * kw[wi] + qj.y * rq1[wi] + kj.y * rk1[wi];
        }
      }
    }
    #pragma unroll
    for (int p = 0; p < 2; ++p)
      #pragma unroll
      for (int wi = 0; wi < 4; ++wi) {
        const float2 s2 = {sacc[p][0][wi], sacc[p][1][wi]};
        *(float2*)&S_s[p][wl + wi][j0] = s2;
      }
    __syncthreads();
    // ---- softmax over j per (p,w) row: 8 lanes/row
    {
      const int row = tid >> 3, sub = tid & 7;
      float* Sr = &S_s[row >> 5][row & 31][0];
      const int jbase = sub * 16;
      float m = -1e30f;
      #pragma unroll
      for (int s = 0; s < 8; ++s) {
        const float2 xv = *(const float2*)&Sr[jbase + s * 2];
        m = fmaxf(m, fmaxf(xv.x, xv.y));
      }
      m = fmaxf(m, __shfl_xor(m, 1));
      m = fmaxf(m, __shfl_xor(m, 2));
      m = fmaxf(m, __shfl_xor(m, 4));
      float Z = 0.f;
      #pragma unroll
      for (int s = 0; s < 8; ++s) {
        float2 xv = *(const float2*)&Sr[jbase + s * 2];
        xv.x = __expf(xv.x - m); xv.y = __expf(xv.y - m);
        Z += xv.x + xv.y;
        *(float2*)&Sr[jbase + s * 2] = xv;
      }
      Z += __shfl_xor(Z, 1);
      Z += __shfl_xor(Z, 2);
      Z += __shfl_xor(Z, 4);
      const float rz = 1.f / Z;
      #pragma unroll
      for (int s = 0; s < 8; ++s) {
        float2 xv = *(const float2*)&Sr[jbase + s * 2];
        xv.x *= rz; xv.y *= rz;
        *(float2*)&Sr[jbase + s * 2] = xv;
      }
    }
    __syncthreads();
    // ---- out += P * (v' + rv')   (thread: oc, 2 j-halves x 2 j)
    {
      const int rvb = ((h * 16 + oc) * WW + w0) * WW + jg * 2;
      #pragma unroll 4
      for (int w2 = 0; w2 < 32; ++w2) {
        float vv[2];
        #pragma unroll
        for (int p = 0; p < 2; ++p) vv[p] = v_s[p][oc][w2];
        #pragma unroll
        for (int jh = 0; jh < 2; ++jh) {
          const float2 rvf = __half22float2(*(const __half2*)&RVT[rvb + w2 * WW + jh * 64]);
          #pragma unroll
          for (int p = 0; p < 2; ++p) {
            const float2 P2 = *(const float2*)&S_s[p][w2][jh * 64 + jg * 2];
            o[p][jh][0] += P2.x * (vv[p] + rvf.x);
            o[p][jh][1] += P2.y * (vv[p] + rvf.y);
          }
        }
      }
    }
    __syncthreads();
  }
  #pragma unroll
  for (int p = 0; p < 2; ++p)
    #pragma unroll
    for (int jh = 0; jh < 2; ++jh) {
      *(__half2*)&ATT[((size_t)((pb + p) * CH + h * 16 + oc) * HH + ii) * WW + jh * 64 + jg * 2] =
          mkh2(o[p][jh][0], o[p][jh][1]);
    }
}

// ---------------------------------------------------------------- launch
extern "C" void kernel_launch(void* const* d_in, const int* in_sizes, int n_in,
                              void* d_out, int out_size, void* d_ws, size_t ws_size,
                              hipStream_t stream) {
  (void)in_sizes; (void)n_in; (void)out_size; (void)ws_size;
  const float* x   = (const float*)d_in[0];
  const float* wq  = (const float*)d_in[1];
  const float* wk  = (const float*)d_in[2];
  const float* wv  = (const float*)d_in[3];
  const float* wo  = (const float*)d_in[4];
  const float* rq  = (const float*)d_in[5];
  const float* rk  = (const float*)d_in[6];
  const float* rv  = (const float*)d_in[7];
  const float* Gq  = (const float*)d_in[8];
  const float* Gk  = (const float*)d_in[9];
  const float* Gv1 = (const float*)d_in[10];
  const float* Gv2 = (const float*)d_in[11];
  float* out = (float*)d_out;

  __half* q16  = (__half*)d_ws;
  __half* k16  = q16 + (size_t)NB * CHW;
  __half* v16  = k16 + (size_t)NB * CHW;          // att aliases v16 (r4-proven safe)
  __half* rq16 = v16 + (size_t)NB * CHW;
  __half* rk16 = rq16 + (size_t)RSZ;
  __half* rv16 = rk16 + (size_t)RSZ;
  __half* W16  = rv16 + (size_t)RSZ;              // [1024][256]: wq,wk,wv,wo stacked

  cvt_w<<<dim3(256), dim3(256), 0, stream>>>(wq, wk, wv, wo, W16);
  cvt_rqrk<<<dim3(4096, 2), dim3(256), 0, stream>>>(rq, rk, Gq, Gk, rq16, rk16);
  cvt_rv_t<<<dim3(4096), dim3(256), 0, stream>>>(rv, Gv2, rv16);
  gemm16<1, 0><<<dim3(3072), dim3(256), 0, stream>>>(W16, x, nullptr, q16, k16, v16,
                                                     nullptr, 0, 6);
  attn_fused<<<dim3(4096), dim3(512), 0, stream>>>(q16, k16, v16, rq16, rk16, rv16, Gv1, v16);
  gemm16<0, 1><<<dim3(1024), dim3(256), 0, stream>>>(W16, nullptr, v16, nullptr, nullptr,
                                                     nullptr, out, 768, 2);
}